// Round 6
// baseline (764.224 us; speedup 1.0000x reference)
//
#include <hip/hip_runtime.h>
#include <hip/hip_bf16.h>

// Problem constants
#define T_ 15
#define CIN_ 6
#define F_ 64
#define HW_ 256      // output spatial
#define PW_ 260      // padded pooled width
#define THRESH_ 15.0f
#define TAU_NEVER 15

typedef float v4f __attribute__((ext_vector_type(4)));

// MONOTONICITY: x = clip(cumsum(ev)) is nondecreasing in t, and all weights are
// positive (0.8 + 0.05*N(0,1), fixed seed). pot[t] is nondecreasing in t: per
// (f,pixel) spikes = {t >= s}; winner/val/count fixed at first crossing e_p.
// spk is a pure function of (rec_wch, rec_e) -> rendered densely.

// ---------------------------------------------------------------------------
// pool_tau: tau[c][yy][xx] = first t where 2x2 max of x > 0 (15 = never).
// x monotone in t -> binary search. Borders written here; zero-inits gmax.
// ---------------------------------------------------------------------------
__global__ __launch_bounds__(256) void pool_tau(const float* __restrict__ x,
                                                unsigned char* __restrict__ tau,
                                                unsigned int* __restrict__ gmaxp) {
    int idx = blockIdx.x * 256 + threadIdx.x;
    if (idx == 0) *gmaxp = 0u;
    if (idx >= CIN_ * PW_ * PW_) return;
    int xx = idx % PW_;
    int rest = idx / PW_;
    int yy = rest % PW_;
    int c = rest / PW_;
    unsigned char tv = TAU_NEVER;
    if (xx >= 2 && xx < 258 && yy >= 2 && yy < 258) {
        int i = yy - 2, j = xx - 2;
        const float* b0 = x + ((size_t)c * 512 + 2 * i) * 512 + 2 * j;
        const size_t tstride = (size_t)CIN_ * 512 * 512;
        const float* b = b0 + 14 * tstride;
        float2 a = *(const float2*)b;
        float2 d = *(const float2*)(b + 512);
        if (a.x > 0.f || a.y > 0.f || d.x > 0.f || d.y > 0.f) {
            int lo = 0, hi = 14;
            while (lo < hi) {
                int mid = (lo + hi) >> 1;
                const float* bm = b0 + (size_t)mid * tstride;
                float2 am = *(const float2*)bm;
                float2 dm = *(const float2*)(bm + 512);
                bool on = (am.x > 0.f || am.y > 0.f || dm.x > 0.f || dm.y > 0.f);
                if (on) hi = mid; else lo = mid + 1;
            }
            tv = (unsigned char)lo;
        }
    }
    tau[idx] = tv;   // idx ordering == tau layout [c][yy][xx]
}

// ---------------------------------------------------------------------------
// Phase A (barrier-free t-loop): block = 4 waves; wave g owns a 4x4 pixel
// group, lane = f. Weights staged TRANSPOSED wl2[k][f] (lane stride 64 dwords
// -> 2-way bank access, conflict-free). Per t: fp32 conv in exact (c,ki,kj)
// order (verified), then per-pixel cross-f max/argmax via 6-step shfl_xor
// butterfly on u64 key (value_bits<<6 | (63-f)) -> first-max tie = lowest f.
// Wave-local done mask + early exit; no per-t __syncthreads.
// ---------------------------------------------------------------------------
__global__ __launch_bounds__(256, 3) void phaseA(const unsigned char* __restrict__ tau,
                                                 const float* __restrict__ w,
                                                 int* __restrict__ rec_wch,
                                                 float* __restrict__ rec_val,
                                                 int* __restrict__ rec_e,
                                                 unsigned int* __restrict__ gmaxp) {
    __shared__ float wl2[150 * 64];                // [k][f], 37.5 KB
    __shared__ unsigned char tw[CIN_ * 144];       // tau window [6][12][12]
    __shared__ float wmax[4];

    const int tid = threadIdx.x;
    const int lane = tid & 63;
    const int g = tid >> 6;
    const int gx = (g & 1) * 4;
    const int gy = (g >> 1) * 4;
    const int px0 = blockIdx.x * 8;
    const int py0 = blockIdx.y * 8;

    // stage transposed weights: wl2[k*64+f] = w[f*150+k]
    for (int idx = tid; idx < 9600; idx += 256) {
        int k = idx >> 6, f = idx & 63;
        wl2[idx] = w[f * 150 + k];
    }
    // stage tau window [6][12][12]
    for (int idx = tid; idx < CIN_ * 144; idx += 256) {
        int c = idx / 144;
        int rem = idx - c * 144;
        int r = rem / 12;
        int xx = rem - r * 12;
        tw[idx] = tau[(c * PW_ + (py0 + r)) * PW_ + (px0 + xx)];
    }
    __syncthreads();

    unsigned int done = 0;                 // wave-uniform bitmask of 16 pixels
    int myw = -1, mye = T_;                // lane i<16 holds pixel i's result
    float myv = 0.0f;
    float wavemax = 0.0f;                  // wave-uniform

    for (int t = 0; t < T_; ++t) {
        float acc[16];
#pragma unroll
        for (int i = 0; i < 16; ++i) acc[i] = 0.0f;

        for (int c = 0; c < CIN_; ++c) {
            // binary window P[t] = (tau <= t), broadcast u32 reads
            float win[8][8];
            const unsigned char* tb = &tw[c * 144 + gy * 12 + gx];
#pragma unroll
            for (int r = 0; r < 8; ++r) {
                unsigned int lo = *(const unsigned int*)(tb + r * 12);
                unsigned int hi = *(const unsigned int*)(tb + r * 12 + 4);
#pragma unroll
                for (int b = 0; b < 4; ++b) {
                    win[r][b]     = (((lo >> (8 * b)) & 0xFF) <= (unsigned)t) ? 1.0f : 0.0f;
                    win[r][4 + b] = (((hi >> (8 * b)) & 0xFF) <= (unsigned)t) ? 1.0f : 0.0f;
                }
            }
#pragma unroll
            for (int ki = 0; ki < 5; ++ki)
#pragma unroll
                for (int kj = 0; kj < 5; ++kj) {
                    float wv = wl2[((c * 25 + ki * 5 + kj) << 6) + lane];
#pragma unroll
                    for (int py = 0; py < 4; ++py)
#pragma unroll
                        for (int px = 0; px < 4; ++px)
                            acc[py * 4 + px] += win[py + ki][px + kj] * wv;
                }
        }

        // per-pixel cross-f argmax (first-max tie) for not-yet-done pixels
#pragma unroll
        for (int i = 0; i < 16; ++i) {
            if (done & (1u << i)) continue;          // wave-uniform
            float v = acc[i];
            v = (v < THRESH_) ? 0.0f : v;
            if (__any(v > 0.0f)) {
                unsigned long long key =
                    ((unsigned long long)__float_as_uint(v) << 6) | (unsigned)(63 - lane);
#pragma unroll
                for (int m = 1; m < 64; m <<= 1) {
                    unsigned long long o = __shfl_xor(key, m, 64);
                    if (o > key) key = o;
                }
                float mv = __uint_as_float((unsigned int)(key >> 6));
                int wf = 63 - (int)(key & 63ULL);
                done |= (1u << i);
                if (lane == i) { myw = wf; myv = mv; mye = t; }
                wavemax = fmaxf(wavemax, mv);
            }
        }
        if (done == 0xFFFFu) break;                  // wave-uniform exit
    }

    if (lane < 16) {
        int py = lane >> 2, px = lane & 3;
        int p = (py0 + gy + py) * HW_ + (px0 + gx + px);
        rec_wch[p] = myw;
        rec_val[p] = myv;
        rec_e[p] = mye;
    }
    if (lane == 0) wmax[g] = wavemax;
    __syncthreads();
    if (tid == 0) {
        float m = fmaxf(fmaxf(wmax[0], wmax[1]), fmaxf(wmax[2], wmax[3]));
        if (m > 0.0f) atomicMax(gmaxp, __float_as_uint(m));
    }
}

// ---------------------------------------------------------------------------
// Dense spk renderer: out[t][f][px] = (wch[px]==f && t>=e[px]) ? 1 : 0.
// Full 64B-line nontemporal float4 stores (write-once stream, skip L2).
// ---------------------------------------------------------------------------
__global__ __launch_bounds__(256) void render(const int* __restrict__ rec_wch,
                                              const int* __restrict__ rec_e,
                                              float* __restrict__ out) {
    const int tid = threadIdx.x;
    const int t = blockIdx.y;
    const int px = blockIdx.x * 1024 + tid * 4;

    int4 wch4 = *(const int4*)(rec_wch + px);
    int4 e4   = *(const int4*)(rec_e + px);
    int s0 = (wch4.x >= 0 && t >= e4.x) ? wch4.x : -1;
    int s1 = (wch4.y >= 0 && t >= e4.y) ? wch4.y : -1;
    int s2 = (wch4.z >= 0 && t >= e4.z) ? wch4.z : -1;
    int s3 = (wch4.w >= 0 && t >= e4.w) ? wch4.w : -1;

    float* base = out + (((size_t)t * F_) << 16) + px;
#pragma unroll
    for (int f = 0; f < F_; ++f) {
        v4f v;
        v.x = (f == s0) ? 1.0f : 0.0f;
        v.y = (f == s1) ? 1.0f : 0.0f;
        v.z = (f == s2) ? 1.0f : 0.0f;
        v.w = (f == s3) ? 1.0f : 0.0f;
        __builtin_nontemporal_store(v, (v4f*)(base + ((size_t)f << 16)));
    }
}

// ---------------------------------------------------------------------------
// select_winners (single block, 1024 thr): per-thread 64 pixels in registers.
// total[i] = reference's sequential fp32 sum (cnt copies of val+15*gmax);
// 5 greedy argmax rounds with suppression recheck vs all previous winners
// (equivalent to cumulative zeroing), tie = lowest flat (f<<16|i) via
// packed u64 key (value<<32 | ~flat). Replaces 7 dispatches.
// ---------------------------------------------------------------------------
__global__ __launch_bounds__(1024) void select_winners(const int* __restrict__ rec_wch,
                                                       const float* __restrict__ rec_val,
                                                       const int* __restrict__ rec_e,
                                                       const unsigned int* __restrict__ gmaxp,
                                                       float* __restrict__ out) {
    __shared__ unsigned long long sred[1024];
    __shared__ int wfj[5], wrj[5], wcj[5], wact[5];

    const int tid = threadIdx.x;
    float g = __uint_as_float(*gmaxp);
    float v15 = 15.0f * g;

    float tot[64];
    signed char fc[64];
#pragma unroll 4
    for (int k = 0; k < 64; ++k) {
        int i = k * 1024 + tid;
        int wch = rec_wch[i];
        float tt = 0.0f;
        if (wch >= 0) {
            int e = rec_e[i];
            float base = rec_val[i] + v15;
            for (int t = e; t < T_; ++t) tt += base;   // sequential fp32, cnt=15-e
        }
        tot[k] = tt;
        fc[k] = (signed char)wch;
    }

    for (int round = 0; round < 5; ++round) {
        unsigned long long key = 0ULL;
        for (int k = 0; k < 64; ++k) {
            float v = tot[k];
            if (v <= 0.0f) continue;
            int i = k * 1024 + tid;
            int fch = fc[k];
            int r = i >> 8, c = i & 255;
            bool sup = false;
            for (int j = 0; j < round; ++j) {
                if (!wact[j]) continue;
                int dr = r - wrj[j]; if (dr < 0) dr = -dr;
                int dc = c - wcj[j]; if (dc < 0) dc = -dc;
                if (fch == wfj[j] || (dr <= 2 && dc <= 2)) sup = true;
            }
            if (!sup) {
                int fl = (fch << 16) | i;
                unsigned int comp = 0x7fffffffu - (unsigned int)fl;
                unsigned long long kk =
                    ((unsigned long long)__float_as_uint(v) << 32) | comp;
                if (kk > key) key = kk;
            }
        }
        sred[tid] = key;
        __syncthreads();
        for (int s = 512; s > 0; s >>= 1) {
            if (tid < s) {
                if (sred[tid + s] > sred[tid]) sred[tid] = sred[tid + s];
            }
            __syncthreads();
        }
        if (tid == 0) {
            unsigned long long sk = sred[0];
            float* wout = out + (size_t)T_ * F_ * HW_ * HW_ + round * 3;
            if (sk != 0ULL) {
                int fl = 0x7fffffff - (int)(unsigned int)(sk & 0xffffffffu);
                int f = fl >> 16, r = (fl >> 8) & 255, c = fl & 255;
                wfj[round] = f; wrj[round] = r; wcj[round] = c; wact[round] = 1;
                wout[0] = (float)f; wout[1] = (float)r; wout[2] = (float)c;
            } else {
                wact[round] = 0;
                wout[0] = -1.0f; wout[1] = -1.0f; wout[2] = -1.0f;
            }
        }
        __syncthreads();
    }
}

// ---------------------------------------------------------------------------
extern "C" void kernel_launch(void* const* d_in, const int* in_sizes, int n_in,
                              void* d_out, int out_size, void* d_ws, size_t ws_size,
                              hipStream_t stream) {
    const float* x = (const float*)d_in[0];
    const float* w = (const float*)d_in[1];
    float* out = (float*)d_out;

    char* wsc = (char*)d_ws;
    unsigned char* tau = (unsigned char*)wsc;
    size_t off = (size_t)CIN_ * PW_ * PW_;            // 405,600 (16B aligned)
    int* rec_wch = (int*)(wsc + off);        off += 65536 * sizeof(int);
    float* rec_val = (float*)(wsc + off);    off += 65536 * sizeof(float);
    int* rec_e = (int*)(wsc + off);          off += 65536 * sizeof(int);
    unsigned int* gmaxp = (unsigned int*)(wsc + off);

    pool_tau<<<(CIN_ * PW_ * PW_ + 255) / 256, 256, 0, stream>>>(x, tau, gmaxp);
    phaseA<<<dim3(32, 32), 256, 0, stream>>>(tau, w, rec_wch, rec_val, rec_e, gmaxp);
    render<<<dim3(64, 15), 256, 0, stream>>>(rec_wch, rec_e, out);
    select_winners<<<1, 1024, 0, stream>>>(rec_wch, rec_val, rec_e, gmaxp, out);
}

// Round 7
// 473.184 us; speedup vs baseline: 1.6151x; 1.6151x over previous
//
#include <hip/hip_runtime.h>
#include <hip/hip_bf16.h>

// Problem constants
#define T_ 15
#define CIN_ 6
#define F_ 64
#define HW_ 256      // output spatial
#define PW_ 260      // padded pooled width
#define THRESH_ 15.0f
#define TAU_NEVER 15

typedef float v4f __attribute__((ext_vector_type(4)));

// MONOTONICITY: x = clip(cumsum(ev)) is nondecreasing in t, and all weights are
// positive (0.8 + 0.05*N(0,1), fixed seed). pot[t] is nondecreasing in t: per
// (f,pixel) spikes = {t >= s}; winner/val/count fixed at first crossing e_p.
// spk is a pure function of (rec_wch, rec_e) -> rendered densely.
//
// R6 lesson: single-block select_winners with tot[64]/fc[64] spilled to
// scratch (VGPR_Count=8, 332us). Tail reverted to grid-parallel dispatches.

// ---------------------------------------------------------------------------
// pool_tau: tau[c][yy][xx] = first t where 2x2 max of x > 0 (15 = never).
// x monotone in t -> binary search. Borders written here; inits slots+gmax.
// ---------------------------------------------------------------------------
__global__ __launch_bounds__(256) void pool_tau(const float* __restrict__ x,
                                                unsigned char* __restrict__ tau,
                                                unsigned long long* __restrict__ slots,
                                                unsigned int* __restrict__ gmaxp) {
    int idx = blockIdx.x * 256 + threadIdx.x;
    if (idx < 5) slots[idx] = 0ULL;
    if (idx == 5) *gmaxp = 0u;
    if (idx >= CIN_ * PW_ * PW_) return;
    int xx = idx % PW_;
    int rest = idx / PW_;
    int yy = rest % PW_;
    int c = rest / PW_;
    unsigned char tv = TAU_NEVER;
    if (xx >= 2 && xx < 258 && yy >= 2 && yy < 258) {
        int i = yy - 2, j = xx - 2;
        const float* b0 = x + ((size_t)c * 512 + 2 * i) * 512 + 2 * j;
        const size_t tstride = (size_t)CIN_ * 512 * 512;
        const float* b = b0 + 14 * tstride;
        float2 a = *(const float2*)b;
        float2 d = *(const float2*)(b + 512);
        if (a.x > 0.f || a.y > 0.f || d.x > 0.f || d.y > 0.f) {
            int lo = 0, hi = 14;
            while (lo < hi) {
                int mid = (lo + hi) >> 1;
                const float* bm = b0 + (size_t)mid * tstride;
                float2 am = *(const float2*)bm;
                float2 dm = *(const float2*)(bm + 512);
                bool on = (am.x > 0.f || am.y > 0.f || dm.x > 0.f || dm.y > 0.f);
                if (on) hi = mid; else lo = mid + 1;
            }
            tv = (unsigned char)lo;
        }
    }
    tau[idx] = tv;   // idx ordering == tau layout [c][yy][xx]
}

// ---------------------------------------------------------------------------
// Phase A (barrier-free t-loop): block = 4 waves; wave g owns a 4x4 pixel
// group, lane = f. Weights staged TRANSPOSED wl2[k][f] (lane stride 64 dwords
// -> conflict-free). Per t: fp32 conv in exact (c,ki,kj) order (verified),
// then per-pixel cross-f max/argmax via 6-step shfl_xor butterfly on u64 key
// (value_bits<<6 | (63-f)) -> first-max tie = lowest f. Wave-local done mask
// + early exit; no per-t __syncthreads.
// ---------------------------------------------------------------------------
__global__ __launch_bounds__(256, 3) void phaseA(const unsigned char* __restrict__ tau,
                                                 const float* __restrict__ w,
                                                 int* __restrict__ rec_wch,
                                                 float* __restrict__ rec_val,
                                                 int* __restrict__ rec_e,
                                                 unsigned int* __restrict__ gmaxp) {
    __shared__ float wl2[150 * 64];                // [k][f], 37.5 KB
    __shared__ unsigned char tw[CIN_ * 144];       // tau window [6][12][12]
    __shared__ float wmax[4];

    const int tid = threadIdx.x;
    const int lane = tid & 63;
    const int g = tid >> 6;
    const int gx = (g & 1) * 4;
    const int gy = (g >> 1) * 4;
    const int px0 = blockIdx.x * 8;
    const int py0 = blockIdx.y * 8;

    // stage transposed weights: wl2[k*64+f] = w[f*150+k]
    for (int idx = tid; idx < 9600; idx += 256) {
        int k = idx >> 6, f = idx & 63;
        wl2[idx] = w[f * 150 + k];
    }
    // stage tau window [6][12][12]
    for (int idx = tid; idx < CIN_ * 144; idx += 256) {
        int c = idx / 144;
        int rem = idx - c * 144;
        int r = rem / 12;
        int xx = rem - r * 12;
        tw[idx] = tau[(c * PW_ + (py0 + r)) * PW_ + (px0 + xx)];
    }
    __syncthreads();

    unsigned int done = 0;                 // wave-uniform bitmask of 16 pixels
    int myw = -1, mye = T_;                // lane i<16 holds pixel i's result
    float myv = 0.0f;
    float wavemax = 0.0f;                  // wave-uniform

    for (int t = 0; t < T_; ++t) {
        float acc[16];
#pragma unroll
        for (int i = 0; i < 16; ++i) acc[i] = 0.0f;

        for (int c = 0; c < CIN_; ++c) {
            // binary window P[t] = (tau <= t), broadcast u32 reads
            float win[8][8];
            const unsigned char* tb = &tw[c * 144 + gy * 12 + gx];
#pragma unroll
            for (int r = 0; r < 8; ++r) {
                unsigned int lo = *(const unsigned int*)(tb + r * 12);
                unsigned int hi = *(const unsigned int*)(tb + r * 12 + 4);
#pragma unroll
                for (int b = 0; b < 4; ++b) {
                    win[r][b]     = (((lo >> (8 * b)) & 0xFF) <= (unsigned)t) ? 1.0f : 0.0f;
                    win[r][4 + b] = (((hi >> (8 * b)) & 0xFF) <= (unsigned)t) ? 1.0f : 0.0f;
                }
            }
#pragma unroll
            for (int ki = 0; ki < 5; ++ki)
#pragma unroll
                for (int kj = 0; kj < 5; ++kj) {
                    float wv = wl2[((c * 25 + ki * 5 + kj) << 6) + lane];
#pragma unroll
                    for (int py = 0; py < 4; ++py)
#pragma unroll
                        for (int px = 0; px < 4; ++px)
                            acc[py * 4 + px] += win[py + ki][px + kj] * wv;
                }
        }

        // per-pixel cross-f argmax (first-max tie) for not-yet-done pixels
#pragma unroll
        for (int i = 0; i < 16; ++i) {
            if (done & (1u << i)) continue;          // wave-uniform
            float v = acc[i];
            v = (v < THRESH_) ? 0.0f : v;
            if (__any(v > 0.0f)) {
                unsigned long long key =
                    ((unsigned long long)__float_as_uint(v) << 6) | (unsigned)(63 - lane);
#pragma unroll
                for (int m = 1; m < 64; m <<= 1) {
                    unsigned long long o = __shfl_xor(key, m, 64);
                    if (o > key) key = o;
                }
                float mv = __uint_as_float((unsigned int)(key >> 6));
                int wf = 63 - (int)(key & 63ULL);
                done |= (1u << i);
                if (lane == i) { myw = wf; myv = mv; mye = t; }
                wavemax = fmaxf(wavemax, mv);
            }
        }
        if (done == 0xFFFFu) break;                  // wave-uniform exit
    }

    if (lane < 16) {
        int py = lane >> 2, px = lane & 3;
        int p = (py0 + gy + py) * HW_ + (px0 + gx + px);
        rec_wch[p] = myw;
        rec_val[p] = myv;
        rec_e[p] = mye;
    }
    if (lane == 0) wmax[g] = wavemax;
    __syncthreads();
    if (tid == 0) {
        float m = fmaxf(fmaxf(wmax[0], wmax[1]), fmaxf(wmax[2], wmax[3]));
        if (m > 0.0f) atomicMax(gmaxp, __float_as_uint(m));
    }
}

// ---------------------------------------------------------------------------
// Dense spk renderer: out[t][f][px] = (wch[px]==f && t>=e[px]) ? 1 : 0.
// Full 64B-line nontemporal float4 stores (write-once stream).
// ---------------------------------------------------------------------------
__global__ __launch_bounds__(256) void render(const int* __restrict__ rec_wch,
                                              const int* __restrict__ rec_e,
                                              float* __restrict__ out) {
    const int tid = threadIdx.x;
    const int t = blockIdx.y;
    const int px = blockIdx.x * 1024 + tid * 4;

    int4 wch4 = *(const int4*)(rec_wch + px);
    int4 e4   = *(const int4*)(rec_e + px);
    int s0 = (wch4.x >= 0 && t >= e4.x) ? wch4.x : -1;
    int s1 = (wch4.y >= 0 && t >= e4.y) ? wch4.y : -1;
    int s2 = (wch4.z >= 0 && t >= e4.z) ? wch4.z : -1;
    int s3 = (wch4.w >= 0 && t >= e4.w) ? wch4.w : -1;

    float* base = out + (((size_t)t * F_) << 16) + px;
#pragma unroll
    for (int f = 0; f < F_; ++f) {
        v4f v;
        v.x = (f == s0) ? 1.0f : 0.0f;
        v.y = (f == s1) ? 1.0f : 0.0f;
        v.z = (f == s2) ? 1.0f : 0.0f;
        v.w = (f == s3) ? 1.0f : 0.0f;
        __builtin_nontemporal_store(v, (v4f*)(base + ((size_t)f << 16)));
    }
}

// ---------------------------------------------------------------------------
// build_keys: per pixel pack the whole decision into one u64:
//   total<=0 -> 0; else (total_bits<<32) | (0x7fffffff - (fch<<16 | i)).
// total = reference's sequential fp32 sum = cnt copies of (val + 15*gmax).
// ---------------------------------------------------------------------------
__global__ __launch_bounds__(256) void build_keys(const int* __restrict__ rec_wch,
                                                  const float* __restrict__ rec_val,
                                                  const int* __restrict__ rec_e,
                                                  const unsigned int* __restrict__ gmaxp,
                                                  unsigned long long* __restrict__ keys) {
    int i0 = (blockIdx.x * 256 + threadIdx.x) * 4;
    float g = __uint_as_float(*gmaxp);
    float v15 = 15.0f * g;
    int4 wch4 = *(const int4*)(rec_wch + i0);
    float4 val4 = *(const float4*)(rec_val + i0);
    int4 e4 = *(const int4*)(rec_e + i0);
#pragma unroll
    for (int q = 0; q < 4; ++q) {
        int wch = (q == 0) ? wch4.x : (q == 1) ? wch4.y : (q == 2) ? wch4.z : wch4.w;
        float val = (q == 0) ? val4.x : (q == 1) ? val4.y : (q == 2) ? val4.z : val4.w;
        int e = (q == 0) ? e4.x : (q == 1) ? e4.y : (q == 2) ? e4.z : e4.w;
        unsigned long long key = 0ULL;
        if (wch >= 0) {
            float base = val + v15;
            float tot = 0.0f;
            for (int t = e; t < T_; ++t) tot += base;   // sequential fp32, cnt=15-e
            if (tot > 0.0f) {
                int fl = (wch << 16) | (i0 + q);
                key = ((unsigned long long)__float_as_uint(tot) << 32)
                    | (0x7fffffffu - (unsigned int)fl);
            }
        }
        keys[i0 + q] = key;
    }
}

// ---------------------------------------------------------------------------
// max_round r: grid-wide argmax over keys with on-the-fly suppression by the
// r previous winners (decoded from slots). Key order = (value, lowest flat
// index) -> exact reference tie-break. Wave shfl reduce + 1 atomicMax/wave.
// ---------------------------------------------------------------------------
__global__ __launch_bounds__(256) void max_round(const unsigned long long* __restrict__ keys,
                                                 unsigned long long* __restrict__ slots,
                                                 int round) {
    int i0 = (blockIdx.x * 256 + threadIdx.x) * 4;

    // previous winners (L2-hot reads, wave-uniform)
    int wf[4], wr[4], wc[4];
    int nprev = 0;
    for (int j = 0; j < round; ++j) {
        unsigned long long s = slots[j];
        if (s == 0ULL) continue;
        int fl = 0x7fffffff - (int)(unsigned int)(s & 0xffffffffu);
        wf[nprev] = fl >> 16; wr[nprev] = (fl >> 8) & 255; wc[nprev] = fl & 255;
        ++nprev;
    }

    unsigned long long best = 0ULL;
#pragma unroll
    for (int q = 0; q < 4; ++q) {
        unsigned long long k = keys[i0 + q];
        if (k == 0ULL) continue;
        int fl = 0x7fffffff - (int)(unsigned int)(k & 0xffffffffu);
        int fch = fl >> 16, r = (fl >> 8) & 255, c = fl & 255;
        bool sup = false;
        for (int j = 0; j < nprev; ++j) {
            int dr = r - wr[j]; if (dr < 0) dr = -dr;
            int dc = c - wc[j]; if (dc < 0) dc = -dc;
            if (fch == wf[j] || (dr <= 2 && dc <= 2)) sup = true;
        }
        if (!sup && k > best) best = k;
    }
#pragma unroll
    for (int m = 1; m < 64; m <<= 1) {
        unsigned long long o = __shfl_xor(best, m, 64);
        if (o > best) best = o;
    }
    if ((threadIdx.x & 63) == 0 && best != 0ULL)
        atomicMax(&slots[round], best);
}

// ---------------------------------------------------------------------------
__global__ void writer(const unsigned long long* __restrict__ slots,
                       float* __restrict__ out) {
    int r = threadIdx.x;
    if (r < 5) {
        unsigned long long s = slots[r];
        float* wout = out + (size_t)T_ * F_ * HW_ * HW_ + r * 3;
        if (s != 0ULL) {
            int fl = 0x7fffffff - (int)(unsigned int)(s & 0xffffffffu);
            wout[0] = (float)(fl >> 16);
            wout[1] = (float)((fl >> 8) & 255);
            wout[2] = (float)(fl & 255);
        } else {
            wout[0] = -1.0f; wout[1] = -1.0f; wout[2] = -1.0f;
        }
    }
}

// ---------------------------------------------------------------------------
extern "C" void kernel_launch(void* const* d_in, const int* in_sizes, int n_in,
                              void* d_out, int out_size, void* d_ws, size_t ws_size,
                              hipStream_t stream) {
    const float* x = (const float*)d_in[0];
    const float* w = (const float*)d_in[1];
    float* out = (float*)d_out;

    char* wsc = (char*)d_ws;
    unsigned char* tau = (unsigned char*)wsc;
    size_t off = (size_t)CIN_ * PW_ * PW_;            // 405,600 (16B aligned)
    int* rec_wch = (int*)(wsc + off);        off += 65536 * sizeof(int);
    float* rec_val = (float*)(wsc + off);    off += 65536 * sizeof(float);
    int* rec_e = (int*)(wsc + off);          off += 65536 * sizeof(int);
    unsigned long long* keys = (unsigned long long*)(wsc + off);  off += 65536 * sizeof(unsigned long long);
    unsigned long long* slots = (unsigned long long*)(wsc + off); off += 8 * sizeof(unsigned long long);
    unsigned int* gmaxp = (unsigned int*)(wsc + off);

    pool_tau<<<(CIN_ * PW_ * PW_ + 255) / 256, 256, 0, stream>>>(x, tau, slots, gmaxp);
    phaseA<<<dim3(32, 32), 256, 0, stream>>>(tau, w, rec_wch, rec_val, rec_e, gmaxp);
    render<<<dim3(64, 15), 256, 0, stream>>>(rec_wch, rec_e, out);
    build_keys<<<64, 256, 0, stream>>>(rec_wch, rec_val, rec_e, gmaxp, keys);
    for (int r = 0; r < 5; ++r)
        max_round<<<64, 256, 0, stream>>>(keys, slots, r);
    writer<<<1, 64, 0, stream>>>(slots, out);
}